// Round 3
// baseline (731.904 us; speedup 1.0000x reference)
//
#include <hip/hip_runtime.h>
#include <stdint.h>
#include <stddef.h>

#define T_TOK 4096   // B*S
#define DD    1024   // D
#define FF    4096   // F
#define EE    8      // experts
#define MAXROWS 9216
#define MAXTILES 72

typedef unsigned short u16;
typedef unsigned int   u32;
typedef short  sh8 __attribute__((ext_vector_type(8)));
typedef __bf16 bf8 __attribute__((ext_vector_type(8)));
typedef float  fl4 __attribute__((ext_vector_type(4)));

__device__ __forceinline__ u32 f2b_u(float f){
  u32 u = __float_as_uint(f);
  return (u + 0x7FFFu + ((u >> 16) & 1u)) >> 16;   // RNE
}
__device__ __forceinline__ u16 f2b(float f){ return (u16)f2b_u(f); }
__device__ __forceinline__ u32 pack2(float a, float b){ return f2b_u(a) | (f2b_u(b) << 16); }

__device__ __forceinline__ void gl_lds16(const u16* g, u16* l){
  __builtin_amdgcn_global_load_lds(
      (const __attribute__((address_space(1))) u32*)(g),
      (__attribute__((address_space(3))) u32*)(l), 16, 0, 0);
}

__device__ __forceinline__ fl4 mfma16(sh8 a, sh8 b, fl4 c){
  return __builtin_amdgcn_mfma_f32_16x16x32_bf16(
      __builtin_bit_cast(bf8, a), __builtin_bit_cast(bf8, b), c, 0, 0, 0);
}

// fast gelu (tanh form)
__device__ __forceinline__ float gelu_f(float x){
  float x2 = x * x;
  float t  = fmaf(0.07135481283f, x2, 1.5957691216f);
  float u  = x * t;
  float e  = __expf(-u);
  return x * __frcp_rn(1.0f + e);
}

// ---------------------------------------------------------------- x -> bf16
__global__ __launch_bounds__(256) void k_cvt_x(const float* __restrict__ x,
                                               u16* __restrict__ xb){
  size_t i = ((size_t)blockIdx.x * 256 + threadIdx.x) * 8;
  float4 a = *(const float4*)(x + i);
  float4 b = *(const float4*)(x + i + 4);
  uint4 v;
  v.x = pack2(a.x, a.y); v.y = pack2(a.z, a.w);
  v.z = pack2(b.x, b.y); v.w = pack2(b.z, b.w);
  *(uint4*)(xb + i) = v;
}

// ---------------------------------------------------------------- gating
__global__ __launch_bounds__(256) void k_gate(const float* __restrict__ x,
    const float* __restrict__ gw, const float* __restrict__ gb,
    int* __restrict__ tidx, float* __restrict__ tp, int* __restrict__ meta){
  int lane = threadIdx.x & 63;
  int t = blockIdx.x * 4 + (threadIdx.x >> 6);
  const float* xr = x + (size_t)t * DD;
  float a0=0,a1=0,a2=0,a3=0,a4=0,a5=0,a6=0,a7=0;
  #pragma unroll
  for (int i = 0; i < 16; i++){
    int d = i * 64 + lane;
    float xv = xr[d];
    const float4* g4 = (const float4*)(gw + (size_t)d * EE);
    float4 p = g4[0], q = g4[1];
    a0 += xv*p.x; a1 += xv*p.y; a2 += xv*p.z; a3 += xv*p.w;
    a4 += xv*q.x; a5 += xv*q.y; a6 += xv*q.z; a7 += xv*q.w;
  }
  #pragma unroll
  for (int off = 32; off > 0; off >>= 1){
    a0 += __shfl_xor(a0, off, 64); a1 += __shfl_xor(a1, off, 64);
    a2 += __shfl_xor(a2, off, 64); a3 += __shfl_xor(a3, off, 64);
    a4 += __shfl_xor(a4, off, 64); a5 += __shfl_xor(a5, off, 64);
    a6 += __shfl_xor(a6, off, 64); a7 += __shfl_xor(a7, off, 64);
  }
  if (lane == 0){
    float l[8] = {a0,a1,a2,a3,a4,a5,a6,a7};
    #pragma unroll
    for (int e = 0; e < 8; e++) l[e] = (l[e] + gb[e]) * (1.0f / 0.9f);
    int i1 = 0;
    #pragma unroll
    for (int e = 1; e < 8; e++) if (l[e] > l[i1]) i1 = e;
    int i2 = (i1 == 0) ? 1 : 0;
    #pragma unroll
    for (int e = 0; e < 8; e++) if (e != i1 && l[e] > l[i2]) i2 = e;
    float ex = expf(l[i2] - l[i1]);
    float inv = 1.0f / (1.0f + ex);
    tidx[2*t] = i1; tidx[2*t+1] = i2;
    tp[2*t] = inv;  tp[2*t+1] = ex * inv;
    atomicAdd(&meta[i1], 1);
    atomicAdd(&meta[i2], 1);
  }
}

// ---------------------------------------------------------------- scan + fill (one block)
__global__ __launch_bounds__(256) void k_fillscan(const int* __restrict__ tidx,
    const float* __restrict__ tp, int* __restrict__ meta,
    int* __restrict__ rowmap, float* __restrict__ rowp){
  __shared__ int sbase[EE];
  __shared__ int scur[EE];
  int tid = threadIdx.x;
  if (tid < EE) scur[tid] = 0;
  if (tid == 0){
    int rowbase = 0, total = 0;
    for (int e = 0; e < EE; e++){
      int c = meta[e];
      sbase[e] = rowbase;
      int nt = (c + 127) >> 7;
      for (int i = 0; i < nt; i++){
        meta[32 + total]  = e;
        meta[104 + total] = rowbase + i * 128;
        total++;
      }
      rowbase += nt << 7;
    }
    meta[24] = total;
  }
  __syncthreads();
  for (int t = tid; t < T_TOK; t += 256){
    #pragma unroll
    for (int k = 0; k < 2; k++){
      int e = tidx[2*t + k];
      int pos = atomicAdd(&scur[e], 1);
      int row = sbase[e] + pos;
      rowmap[row] = (t << 1) | k;
      rowp[row] = tp[2*t + k];
    }
  }
}

// ---------------------------------------------------------------- transpose+convert
// src fp32 [E][R][C] -> dst bf16 [E][C][R]
__global__ __launch_bounds__(256) void k_cvtw(const float* __restrict__ src,
    u16* __restrict__ dst, int R, int C){
  __shared__ float tile[64][65];
  int e = blockIdx.z;
  const float* se = src + (size_t)e * R * C;
  u16* de = dst + (size_t)e * R * C;
  int rblk = blockIdx.y * 64, cblk = blockIdx.x * 64;
  int tid = threadIdx.x;
  int lr = tid >> 4, lc = tid & 15;
  #pragma unroll
  for (int i = 0; i < 4; i++){
    int row = lr + i * 16;
    float4 v = *(const float4*)(se + (size_t)(rblk + row) * C + cblk + lc * 4);
    tile[row][lc*4+0] = v.x; tile[row][lc*4+1] = v.y;
    tile[row][lc*4+2] = v.z; tile[row][lc*4+3] = v.w;
  }
  __syncthreads();
  int c = tid >> 2, seg = tid & 3;
  u32 o[8];
  #pragma unroll
  for (int j = 0; j < 8; j++){
    float f0 = tile[seg*16 + 2*j    ][c];
    float f1 = tile[seg*16 + 2*j + 1][c];
    o[j] = pack2(f0, f1);
  }
  u16* dp = de + (size_t)(cblk + c) * R + rblk + seg * 16;
  *(uint4*)(dp)     = make_uint4(o[0], o[1], o[2], o[3]);
  *(uint4*)(dp + 8) = make_uint4(o[4], o[5], o[6], o[7]);
}

// ---------------------------------------------------------------- GEMM1: H = gelu(Xg @ W1t)
// 128x128 tile, BK=64, XOR-swizzle, double-buffered LDS prefetch pipeline
__global__ __launch_bounds__(256) void k_gemm_h(
    const u16* __restrict__ Xb, const u16* __restrict__ Wt,
    const float* __restrict__ b1, const int* __restrict__ meta,
    const int* __restrict__ rowmap, u16* __restrict__ H){
  __shared__ u16 A0[128*64], B0[128*64], A1[128*64], B1[128*64];
  int tx = blockIdx.x;
  if (tx >= meta[24]) return;
  int e = meta[32 + tx], row0 = meta[104 + tx];
  int n0 = blockIdx.y * 128;
  int tid = threadIdx.x;
  int rsub = tid >> 3;
  int sw_st = ((tid & 7) ^ (rsub & 7)) * 8;
  const u16* Be = Wt + ((size_t)e * FF + n0) * DD;
  const u16* gA[4];
  const u16* gB[4];
  #pragma unroll
  for (int j = 0; j < 4; j++){
    int row = j * 32 + rsub;
    int rm = rowmap[row0 + row];
    int tok = (rm < 0) ? 0 : (rm >> 1);
    gA[j] = Xb + (size_t)tok * DD + sw_st;
    gB[j] = Be + (size_t)row * DD + sw_st;
  }

  int lane = tid & 63, wv = tid >> 6;
  int wm = wv & 1, wn = wv >> 1;
  int lr = lane & 15, lq = lane >> 4;
  int sw0 = ((lq    ) ^ (lr & 7)) * 8;
  int sw1 = ((lq + 4) ^ (lr & 7)) * 8;
  int offA = (wm * 64 + lr) * 64;
  int offB = (wn * 64 + lr) * 64;

  fl4 acc[4][4];
  #pragma unroll
  for (int mi = 0; mi < 4; mi++)
    #pragma unroll
    for (int ni = 0; ni < 4; ni++) acc[mi][ni] = (fl4){0.f,0.f,0.f,0.f};

  auto stage = [&](int k0, u16* dA, u16* dB){
    #pragma unroll
    for (int j = 0; j < 4; j++){
      gl_lds16(gA[j] + k0, dA + tid * 8 + j * 2048);
      gl_lds16(gB[j] + k0, dB + tid * 8 + j * 2048);
    }
  };
  auto compute = [&](const u16* bufA, const u16* bufB){
    #pragma unroll
    for (int kk = 0; kk < 2; kk++){
      int sw = kk ? sw1 : sw0;
      sh8 a[4], b[4];
      #pragma unroll
      for (int mi = 0; mi < 4; mi++) a[mi] = *(const sh8*)(bufA + offA + mi * 1024 + sw);
      #pragma unroll
      for (int ni = 0; ni < 4; ni++) b[ni] = *(const sh8*)(bufB + offB + ni * 1024 + sw);
      #pragma unroll
      for (int mi = 0; mi < 4; mi++)
        #pragma unroll
        for (int ni = 0; ni < 4; ni++)
          acc[mi][ni] = mfma16(a[mi], b[ni], acc[mi][ni]);
    }
  };

  stage(0, A0, B0);
  for (int k0 = 0; k0 < DD; k0 += 128){
    __syncthreads();
    stage(k0 + 64, A1, B1);        // prefetch while computing A0/B0
    compute(A0, B0);
    __syncthreads();
    if (k0 + 128 < DD) stage(k0 + 128, A0, B0);
    compute(A1, B1);
  }

  const float* b1e = b1 + (size_t)e * FF;
  float bias[4];
  #pragma unroll
  for (int ni = 0; ni < 4; ni++) bias[ni] = b1e[n0 + wn*64 + ni*16 + lr];
  #pragma unroll
  for (int mi = 0; mi < 4; mi++){
    int grb = row0 + wm * 64 + mi * 16 + lq * 4;
    #pragma unroll
    for (int ni = 0; ni < 4; ni++){
      int gc = n0 + wn * 64 + ni * 16 + lr;
      #pragma unroll
      for (int r = 0; r < 4; r++){
        float v = acc[mi][ni][r] + bias[ni];
        H[(size_t)(grb + r) * FF + gc] = f2b(gelu_f(v));
      }
    }
  }
}

// ---------------------------------------------------------------- GEMM2 (split-K=2): slots += (H @ W2t [+ b2]) * p
__global__ __launch_bounds__(256) void k_gemm_y(
    const u16* __restrict__ H, const u16* __restrict__ Wt,
    const float* __restrict__ b2, const int* __restrict__ meta,
    const int* __restrict__ rowmap, const float* __restrict__ rowp,
    float* __restrict__ slots){
  __shared__ u16 A0[128*64], B0[128*64], A1[128*64], B1[128*64];
  int tx = blockIdx.x;
  if (tx >= meta[24]) return;
  int e = meta[32 + tx], row0 = meta[104 + tx];
  int n0 = blockIdx.y * 128;
  int kz = blockIdx.z;
  int kbase = kz * (FF / 2);
  int tid = threadIdx.x;
  int rsub = tid >> 3;
  int sw_st = ((tid & 7) ^ (rsub & 7)) * 8;
  const u16* Be = Wt + ((size_t)e * DD + n0) * FF + kbase;
  const u16* gA[4];
  const u16* gB[4];
  #pragma unroll
  for (int j = 0; j < 4; j++){
    int row = j * 32 + rsub;
    gA[j] = H + (size_t)(row0 + row) * FF + kbase + sw_st;
    gB[j] = Be + (size_t)row * FF + sw_st;
  }

  int lane = tid & 63, wv = tid >> 6;
  int wm = wv & 1, wn = wv >> 1;
  int lr = lane & 15, lq = lane >> 4;
  int sw0 = ((lq    ) ^ (lr & 7)) * 8;
  int sw1 = ((lq + 4) ^ (lr & 7)) * 8;
  int offA = (wm * 64 + lr) * 64;
  int offB = (wn * 64 + lr) * 64;

  fl4 acc[4][4];
  #pragma unroll
  for (int mi = 0; mi < 4; mi++)
    #pragma unroll
    for (int ni = 0; ni < 4; ni++) acc[mi][ni] = (fl4){0.f,0.f,0.f,0.f};

  auto stage = [&](int k0, u16* dA, u16* dB){
    #pragma unroll
    for (int j = 0; j < 4; j++){
      gl_lds16(gA[j] + k0, dA + tid * 8 + j * 2048);
      gl_lds16(gB[j] + k0, dB + tid * 8 + j * 2048);
    }
  };
  auto compute = [&](const u16* bufA, const u16* bufB){
    #pragma unroll
    for (int kk = 0; kk < 2; kk++){
      int sw = kk ? sw1 : sw0;
      sh8 a[4], b[4];
      #pragma unroll
      for (int mi = 0; mi < 4; mi++) a[mi] = *(const sh8*)(bufA + offA + mi * 1024 + sw);
      #pragma unroll
      for (int ni = 0; ni < 4; ni++) b[ni] = *(const sh8*)(bufB + offB + ni * 1024 + sw);
      #pragma unroll
      for (int mi = 0; mi < 4; mi++)
        #pragma unroll
        for (int ni = 0; ni < 4; ni++)
          acc[mi][ni] = mfma16(a[mi], b[ni], acc[mi][ni]);
    }
  };

  const int KC = FF / 2;
  stage(0, A0, B0);
  for (int k0 = 0; k0 < KC; k0 += 128){
    __syncthreads();
    stage(k0 + 64, A1, B1);
    compute(A0, B0);
    __syncthreads();
    if (k0 + 128 < KC) stage(k0 + 128, A0, B0);
    compute(A1, B1);
  }

  const float* b2e = b2 + (size_t)e * DD;
  float bias[4];
  #pragma unroll
  for (int ni = 0; ni < 4; ni++)
    bias[ni] = (kz == 0) ? b2e[n0 + wn*64 + ni*16 + lr] : 0.0f;
  #pragma unroll
  for (int mi = 0; mi < 4; mi++){
    int grb = row0 + wm * 64 + mi * 16 + lq * 4;
    #pragma unroll
    for (int r = 0; r < 4; r++){
      int gr = grb + r;
      int sl = rowmap[gr];
      if (sl < 0) continue;
      float p = rowp[gr];
      #pragma unroll
      for (int ni = 0; ni < 4; ni++){
        int gc = n0 + wn * 64 + ni * 16 + lr;
        atomicAdd(&slots[(size_t)sl * DD + gc], (acc[mi][ni][r] + bias[ni]) * p);
      }
    }
  }
}

// ---------------------------------------------------------------- combine + LayerNorm
__global__ __launch_bounds__(256) void k_ln(const float* __restrict__ slots,
    const float* __restrict__ lng, const float* __restrict__ lnb,
    float* __restrict__ out){
  int lane = threadIdx.x & 63;
  int t = blockIdx.x * 4 + (threadIdx.x >> 6);
  const float* s0 = slots + (size_t)(2 * t) * DD;
  const float* s1 = s0 + DD;
  float y[16];
  float sum = 0.f, sq = 0.f;
  #pragma unroll
  for (int i = 0; i < 2; i++){
    int d = lane * 8 + i * 512;
    float4 p0 = *(const float4*)(s0 + d);
    float4 p1 = *(const float4*)(s0 + d + 4);
    float4 q0 = *(const float4*)(s1 + d);
    float4 q1 = *(const float4*)(s1 + d + 4);
    y[i*8+0]=p0.x+q0.x; y[i*8+1]=p0.y+q0.y; y[i*8+2]=p0.z+q0.z; y[i*8+3]=p0.w+q0.w;
    y[i*8+4]=p1.x+q1.x; y[i*8+5]=p1.y+q1.y; y[i*8+6]=p1.z+q1.z; y[i*8+7]=p1.w+q1.w;
  }
  #pragma unroll
  for (int j = 0; j < 16; j++){ sum += y[j]; sq += y[j]*y[j]; }
  #pragma unroll
  for (int off = 32; off > 0; off >>= 1){
    sum += __shfl_xor(sum, off, 64);
    sq  += __shfl_xor(sq,  off, 64);
  }
  float mu = sum * (1.0f / DD);
  float var = sq * (1.0f / DD) - mu * mu;
  float rs = 1.0f / sqrtf(var + 1e-5f);
  #pragma unroll
  for (int i = 0; i < 2; i++){
    int d = lane * 8 + i * 512;
    float4 g0 = *(const float4*)(lng + d), g1 = *(const float4*)(lng + d + 4);
    float4 c0 = *(const float4*)(lnb + d), c1 = *(const float4*)(lnb + d + 4);
    float4 o0, o1;
    o0.x=(y[i*8+0]-mu)*rs*g0.x+c0.x; o0.y=(y[i*8+1]-mu)*rs*g0.y+c0.y;
    o0.z=(y[i*8+2]-mu)*rs*g0.z+c0.z; o0.w=(y[i*8+3]-mu)*rs*g0.w+c0.w;
    o1.x=(y[i*8+4]-mu)*rs*g1.x+c1.x; o1.y=(y[i*8+5]-mu)*rs*g1.y+c1.y;
    o1.z=(y[i*8+6]-mu)*rs*g1.z+c1.z; o1.w=(y[i*8+7]-mu)*rs*g1.w+c1.w;
    *(float4*)(out + (size_t)t * DD + d)     = o0;
    *(float4*)(out + (size_t)t * DD + d + 4) = o1;
  }
}

// ---------------------------------------------------------------- launcher
extern "C" void kernel_launch(void* const* d_in, const int* in_sizes, int n_in,
                              void* d_out, int out_size, void* d_ws, size_t ws_size,
                              hipStream_t stream){
  const float* x   = (const float*)d_in[0];
  const float* gw  = (const float*)d_in[1];
  const float* gb  = (const float*)d_in[2];
  const float* w1  = (const float*)d_in[3];
  const float* b1  = (const float*)d_in[4];
  const float* w2  = (const float*)d_in[5];
  const float* b2  = (const float*)d_in[6];
  const float* lng = (const float*)d_in[7];
  const float* lnb = (const float*)d_in[8];
  float* out = (float*)d_out;

  char* ws = (char*)d_ws;
  size_t off = 0;
  auto alloc = [&](size_t bytes) -> void* {
    void* p = ws + off;
    off = (off + bytes + 255) & ~(size_t)255;
    return p;
  };
  int*   meta   = (int*)  alloc(256 * 4);
  int*   rowmap = (int*)  alloc(MAXROWS * 4);
  float* rowp   = (float*)alloc(MAXROWS * 4);
  int*   tidx   = (int*)  alloc(2 * T_TOK * 4);
  float* tp     = (float*)alloc(2 * T_TOK * 4);
  u16*   Xb     = (u16*)  alloc((size_t)T_TOK * DD * 2);
  float* slots  = (float*)alloc((size_t)T_TOK * 2 * DD * 4);
  u16*   H      = (u16*)  alloc((size_t)MAXROWS * FF * 2);
  u16*   Wt     = (u16*)  alloc((size_t)EE * DD * FF * 2);  // W1^T then W2^T
  (void)ws_size; (void)in_sizes; (void)n_in; (void)out_size;

  hipMemsetAsync(meta, 0, 64, stream);
  hipMemsetAsync(rowmap, 0xFF, MAXROWS * 4, stream);
  hipMemsetAsync(slots, 0, (size_t)T_TOK * 2 * DD * 4, stream);  // atomic accum target

  k_cvt_x   <<<(T_TOK * DD) / (256 * 8), 256, 0, stream>>>(x, Xb);
  k_gate    <<<T_TOK / 4, 256, 0, stream>>>(x, gw, gb, tidx, tp, meta);
  k_fillscan<<<1, 256, 0, stream>>>(tidx, tp, meta, rowmap, rowp);

  // W1: [E][D][F] -> Wt = [E][F][D]
  k_cvtw  <<<dim3(FF / 64, DD / 64, EE), 256, 0, stream>>>(w1, Wt, DD, FF);
  k_gemm_h<<<dim3(MAXTILES, FF / 128), 256, 0, stream>>>(Xb, Wt, b1, meta, rowmap, H);
  // W2: [E][F][D] -> Wt = [E][D][F]
  k_cvtw  <<<dim3(DD / 64, FF / 64, EE), 256, 0, stream>>>(w2, Wt, FF, DD);
  k_gemm_y<<<dim3(MAXTILES, DD / 128, 2), 256, 0, stream>>>(H, Wt, b2, meta, rowmap, rowp, slots);

  k_ln    <<<T_TOK / 4, 256, 0, stream>>>(slots, lng, lnb, out);
}

// Round 4
// 633.105 us; speedup vs baseline: 1.1561x; 1.1561x over previous
//
#include <hip/hip_runtime.h>
#include <stdint.h>
#include <stddef.h>

#define T_TOK 4096   // B*S
#define DD    1024   // D
#define FF    4096   // F
#define EE    8      // experts
#define MAXROWS 9216
#define MAXTILES 72

typedef unsigned short u16;
typedef unsigned int   u32;
typedef short  sh8 __attribute__((ext_vector_type(8)));
typedef __bf16 bf8 __attribute__((ext_vector_type(8)));
typedef float  fl4 __attribute__((ext_vector_type(4)));

__device__ __forceinline__ u32 f2b_u(float f){
  u32 u = __float_as_uint(f);
  return (u + 0x7FFFu + ((u >> 16) & 1u)) >> 16;   // RNE
}
__device__ __forceinline__ u16 f2b(float f){ return (u16)f2b_u(f); }
__device__ __forceinline__ u32 pack2(float a, float b){ return f2b_u(a) | (f2b_u(b) << 16); }

__device__ __forceinline__ void gl_lds16(const u16* g, u16* l){
  __builtin_amdgcn_global_load_lds(
      (const __attribute__((address_space(1))) u32*)(g),
      (__attribute__((address_space(3))) u32*)(l), 16, 0, 0);
}

__device__ __forceinline__ fl4 mfma16(sh8 a, sh8 b, fl4 c){
  return __builtin_amdgcn_mfma_f32_16x16x32_bf16(
      __builtin_bit_cast(bf8, a), __builtin_bit_cast(bf8, b), c, 0, 0, 0);
}

// fast gelu (tanh form)
__device__ __forceinline__ float gelu_f(float x){
  float x2 = x * x;
  float t  = fmaf(0.07135481283f, x2, 1.5957691216f);
  float u  = x * t;
  float e  = __expf(-u);
  return x * __frcp_rn(1.0f + e);
}

// ---------------------------------------------------------------- gating + x->bf16 (fused)
__global__ __launch_bounds__(256) void k_gate_cvt(const float* __restrict__ x,
    const float* __restrict__ gw, const float* __restrict__ gb,
    int* __restrict__ tidx, float* __restrict__ tp, u16* __restrict__ xb){
  int lane = threadIdx.x & 63;
  int t = blockIdx.x * 4 + (threadIdx.x >> 6);
  const float* xr = x + (size_t)t * DD;
  float a0=0,a1=0,a2=0,a3=0,a4=0,a5=0,a6=0,a7=0;
  #pragma unroll
  for (int i = 0; i < 16; i++){
    int d = i * 64 + lane;
    float xv = xr[d];
    const float4* g4 = (const float4*)(gw + (size_t)d * EE);
    float4 p = g4[0], q = g4[1];
    a0 += xv*p.x; a1 += xv*p.y; a2 += xv*p.z; a3 += xv*p.w;
    a4 += xv*q.x; a5 += xv*q.y; a6 += xv*q.z; a7 += xv*q.w;
  }
  // bf16 conversion of this token's row (x row is hot in L1/L2)
  {
    int db = lane * 16;
    float4 va = *(const float4*)(xr + db);
    float4 vb = *(const float4*)(xr + db + 4);
    float4 vc = *(const float4*)(xr + db + 8);
    float4 vd = *(const float4*)(xr + db + 12);
    uint4 o0, o1;
    o0.x = pack2(va.x, va.y); o0.y = pack2(va.z, va.w);
    o0.z = pack2(vb.x, vb.y); o0.w = pack2(vb.z, vb.w);
    o1.x = pack2(vc.x, vc.y); o1.y = pack2(vc.z, vc.w);
    o1.z = pack2(vd.x, vd.y); o1.w = pack2(vd.z, vd.w);
    *(uint4*)(xb + (size_t)t * DD + db)     = o0;
    *(uint4*)(xb + (size_t)t * DD + db + 8) = o1;
  }
  #pragma unroll
  for (int off = 32; off > 0; off >>= 1){
    a0 += __shfl_xor(a0, off, 64); a1 += __shfl_xor(a1, off, 64);
    a2 += __shfl_xor(a2, off, 64); a3 += __shfl_xor(a3, off, 64);
    a4 += __shfl_xor(a4, off, 64); a5 += __shfl_xor(a5, off, 64);
    a6 += __shfl_xor(a6, off, 64); a7 += __shfl_xor(a7, off, 64);
  }
  if (lane == 0){
    float l[8] = {a0,a1,a2,a3,a4,a5,a6,a7};
    #pragma unroll
    for (int e = 0; e < 8; e++) l[e] = (l[e] + gb[e]) * (1.0f / 0.9f);
    int i1 = 0;
    #pragma unroll
    for (int e = 1; e < 8; e++) if (l[e] > l[i1]) i1 = e;
    int i2 = (i1 == 0) ? 1 : 0;
    #pragma unroll
    for (int e = 0; e < 8; e++) if (e != i1 && l[e] > l[i2]) i2 = e;
    float ex = expf(l[i2] - l[i1]);
    float inv = 1.0f / (1.0f + ex);
    tidx[2*t] = i1; tidx[2*t+1] = i2;
    tp[2*t] = inv;  tp[2*t+1] = ex * inv;
  }
}

// ---------------------------------------------------------------- histogram + scan + rowmap init + fill (one block)
// meta: [24]=total tiles [32..103]=tile_expert [104..175]=tile_row0
__global__ __launch_bounds__(256) void k_fillscan(const int* __restrict__ tidx,
    const float* __restrict__ tp, int* __restrict__ meta,
    int* __restrict__ rowmap, float* __restrict__ rowp){
  __shared__ int hist[EE];
  __shared__ int sbase[EE];
  __shared__ int scur[EE];
  int tid = threadIdx.x;
  if (tid < EE){ hist[tid] = 0; scur[tid] = 0; }
  __syncthreads();
  for (int i = tid; i < 2 * T_TOK; i += 256) atomicAdd(&hist[tidx[i]], 1);
  __syncthreads();
  if (tid == 0){
    int rowbase = 0, total = 0;
    for (int e = 0; e < EE; e++){
      sbase[e] = rowbase;
      int nt = (hist[e] + 127) >> 7;
      for (int i = 0; i < nt; i++){
        meta[32 + total]  = e;
        meta[104 + total] = rowbase + i * 128;
        total++;
      }
      rowbase += nt << 7;
    }
    meta[24] = total;
  }
  // rowmap init (padded rows must read -1)
  for (int r = tid; r < MAXROWS; r += 256) rowmap[r] = -1;
  __syncthreads();
  for (int t = tid; t < T_TOK; t += 256){
    #pragma unroll
    for (int k = 0; k < 2; k++){
      int e = tidx[2*t + k];
      int pos = atomicAdd(&scur[e], 1);
      int row = sbase[e] + pos;
      rowmap[row] = (t << 1) | k;
      rowp[row] = tp[2*t + k];
    }
  }
}

// ---------------------------------------------------------------- transpose+convert
// src fp32 [E][R][C] -> dst bf16 [E][C][R]
__global__ __launch_bounds__(256) void k_cvtw(const float* __restrict__ src,
    u16* __restrict__ dst, int R, int C){
  __shared__ float tile[64][65];
  int e = blockIdx.z;
  const float* se = src + (size_t)e * R * C;
  u16* de = dst + (size_t)e * R * C;
  int rblk = blockIdx.y * 64, cblk = blockIdx.x * 64;
  int tid = threadIdx.x;
  int lr = tid >> 4, lc = tid & 15;
  #pragma unroll
  for (int i = 0; i < 4; i++){
    int row = lr + i * 16;
    float4 v = *(const float4*)(se + (size_t)(rblk + row) * C + cblk + lc * 4);
    tile[row][lc*4+0] = v.x; tile[row][lc*4+1] = v.y;
    tile[row][lc*4+2] = v.z; tile[row][lc*4+3] = v.w;
  }
  __syncthreads();
  int c = tid >> 2, seg = tid & 3;
  u32 o[8];
  #pragma unroll
  for (int j = 0; j < 8; j++){
    float f0 = tile[seg*16 + 2*j    ][c];
    float f1 = tile[seg*16 + 2*j + 1][c];
    o[j] = pack2(f0, f1);
  }
  u16* dp = de + (size_t)(cblk + c) * R + rblk + seg * 16;
  *(uint4*)(dp)     = make_uint4(o[0], o[1], o[2], o[3]);
  *(uint4*)(dp + 8) = make_uint4(o[4], o[5], o[6], o[7]);
}

// ---------------------------------------------------------------- GEMM1: H = gelu(Xg @ W1t)
// 128x128 tile, BK=64, single-buffer 32KB LDS, XOR swizzle, XCD-aware remap
__global__ __launch_bounds__(256) void k_gemm_h(
    const u16* __restrict__ Xb, const u16* __restrict__ Wt,
    const float* __restrict__ b1, const int* __restrict__ meta,
    const int* __restrict__ rowmap, u16* __restrict__ H){
  __shared__ u16 As[128 * 64];
  __shared__ u16 Bs[128 * 64];
  int id = blockIdx.y * MAXTILES + blockIdx.x;
  int tx  = id >> 5;         // row-tile: consecutive ids share A-tile
  int nty = id & 31;         // n-tile: per-XCD B-tile working set stays small
  if (tx >= meta[24]) return;
  int e = meta[32 + tx], row0 = meta[104 + tx];
  int n0 = nty * 128;
  int tid = threadIdx.x;
  int rsub = tid >> 3;
  int sw_st = ((tid & 7) ^ (rsub & 7)) * 8;
  const u16* Be = Wt + ((size_t)e * FF + n0) * DD;
  const u16* gA[4];
  const u16* gB[4];
  #pragma unroll
  for (int j = 0; j < 4; j++){
    int row = j * 32 + rsub;
    int rm = rowmap[row0 + row];
    int tok = (rm < 0) ? 0 : (rm >> 1);
    gA[j] = Xb + (size_t)tok * DD + sw_st;
    gB[j] = Be + (size_t)row * DD + sw_st;
  }
  u16* lA = As + tid * 8;
  u16* lB = Bs + tid * 8;

  int lane = tid & 63, wv = tid >> 6;
  int wm = wv & 1, wn = wv >> 1;
  int lr = lane & 15, lq = lane >> 4;
  int sw0 = ((lq    ) ^ (lr & 7)) * 8;
  int sw1 = ((lq + 4) ^ (lr & 7)) * 8;
  const u16* pA = As + (wm * 64 + lr) * 64;
  const u16* pB = Bs + (wn * 64 + lr) * 64;

  fl4 acc[4][4];
  #pragma unroll
  for (int mi = 0; mi < 4; mi++)
    #pragma unroll
    for (int ni = 0; ni < 4; ni++) acc[mi][ni] = (fl4){0.f,0.f,0.f,0.f};

  for (int k0 = 0; k0 < DD; k0 += 64){
    #pragma unroll
    for (int j = 0; j < 4; j++){
      gl_lds16(gA[j] + k0, lA + j * 2048);
      gl_lds16(gB[j] + k0, lB + j * 2048);
    }
    __syncthreads();
    #pragma unroll
    for (int kk = 0; kk < 2; kk++){
      int sw = kk ? sw1 : sw0;
      sh8 a[4], b[4];
      #pragma unroll
      for (int mi = 0; mi < 4; mi++) a[mi] = *(const sh8*)(pA + mi * 1024 + sw);
      #pragma unroll
      for (int ni = 0; ni < 4; ni++) b[ni] = *(const sh8*)(pB + ni * 1024 + sw);
      #pragma unroll
      for (int mi = 0; mi < 4; mi++)
        #pragma unroll
        for (int ni = 0; ni < 4; ni++)
          acc[mi][ni] = mfma16(a[mi], b[ni], acc[mi][ni]);
    }
    __syncthreads();
  }

  const float* b1e = b1 + (size_t)e * FF;
  float bias[4];
  #pragma unroll
  for (int ni = 0; ni < 4; ni++) bias[ni] = b1e[n0 + wn*64 + ni*16 + lr];
  #pragma unroll
  for (int mi = 0; mi < 4; mi++){
    int grb = row0 + wm * 64 + mi * 16 + lq * 4;
    #pragma unroll
    for (int ni = 0; ni < 4; ni++){
      int gc = n0 + wn * 64 + ni * 16 + lr;
      #pragma unroll
      for (int r = 0; r < 4; r++){
        float v = acc[mi][ni][r] + bias[ni];
        H[(size_t)(grb + r) * FF + gc] = f2b(gelu_f(v));
      }
    }
  }
}

// ---------------------------------------------------------------- GEMM2 (split-K=2): slots += (H @ W2t [+ b2]) * p
__global__ __launch_bounds__(256) void k_gemm_y(
    const u16* __restrict__ H, const u16* __restrict__ Wt,
    const float* __restrict__ b2, const int* __restrict__ meta,
    const int* __restrict__ rowmap, const float* __restrict__ rowp,
    float* __restrict__ slots){
  __shared__ u16 As[128 * 64];
  __shared__ u16 Bs[128 * 64];
  int id = blockIdx.y * MAXTILES + blockIdx.x;
  int tx  = id >> 3;
  int nty = id & 7;
  if (tx >= meta[24]) return;
  int e = meta[32 + tx], row0 = meta[104 + tx];
  int n0 = nty * 128;
  int kz = blockIdx.z;
  int kbase = kz * (FF / 2);
  int tid = threadIdx.x;
  int rsub = tid >> 3;
  int sw_st = ((tid & 7) ^ (rsub & 7)) * 8;
  const u16* Be = Wt + ((size_t)e * DD + n0) * FF + kbase;
  const u16* gA[4];
  const u16* gB[4];
  #pragma unroll
  for (int j = 0; j < 4; j++){
    int row = j * 32 + rsub;
    gA[j] = H + (size_t)(row0 + row) * FF + kbase + sw_st;
    gB[j] = Be + (size_t)row * FF + sw_st;
  }
  u16* lA = As + tid * 8;
  u16* lB = Bs + tid * 8;

  int lane = tid & 63, wv = tid >> 6;
  int wm = wv & 1, wn = wv >> 1;
  int lr = lane & 15, lq = lane >> 4;
  int sw0 = ((lq    ) ^ (lr & 7)) * 8;
  int sw1 = ((lq + 4) ^ (lr & 7)) * 8;
  const u16* pA = As + (wm * 64 + lr) * 64;
  const u16* pB = Bs + (wn * 64 + lr) * 64;

  fl4 acc[4][4];
  #pragma unroll
  for (int mi = 0; mi < 4; mi++)
    #pragma unroll
    for (int ni = 0; ni < 4; ni++) acc[mi][ni] = (fl4){0.f,0.f,0.f,0.f};

  const int KC = FF / 2;
  for (int k0 = 0; k0 < KC; k0 += 64){
    #pragma unroll
    for (int j = 0; j < 4; j++){
      gl_lds16(gA[j] + k0, lA + j * 2048);
      gl_lds16(gB[j] + k0, lB + j * 2048);
    }
    __syncthreads();
    #pragma unroll
    for (int kk = 0; kk < 2; kk++){
      int sw = kk ? sw1 : sw0;
      sh8 a[4], b[4];
      #pragma unroll
      for (int mi = 0; mi < 4; mi++) a[mi] = *(const sh8*)(pA + mi * 1024 + sw);
      #pragma unroll
      for (int ni = 0; ni < 4; ni++) b[ni] = *(const sh8*)(pB + ni * 1024 + sw);
      #pragma unroll
      for (int mi = 0; mi < 4; mi++)
        #pragma unroll
        for (int ni = 0; ni < 4; ni++)
          acc[mi][ni] = mfma16(a[mi], b[ni], acc[mi][ni]);
    }
    __syncthreads();
  }

  const float* b2e = b2 + (size_t)e * DD;
  float bias[4];
  #pragma unroll
  for (int ni = 0; ni < 4; ni++)
    bias[ni] = (kz == 0) ? b2e[n0 + wn*64 + ni*16 + lr] : 0.0f;
  #pragma unroll
  for (int mi = 0; mi < 4; mi++){
    int grb = row0 + wm * 64 + mi * 16 + lq * 4;
    #pragma unroll
    for (int r = 0; r < 4; r++){
      int gr = grb + r;
      int sl = rowmap[gr];
      if (sl < 0) continue;
      float p = rowp[gr];
      #pragma unroll
      for (int ni = 0; ni < 4; ni++){
        int gc = n0 + wn * 64 + ni * 16 + lr;
        atomicAdd(&slots[(size_t)sl * DD + gc], (acc[mi][ni][r] + bias[ni]) * p);
      }
    }
  }
}

// ---------------------------------------------------------------- combine + LayerNorm
__global__ __launch_bounds__(256) void k_ln(const float* __restrict__ slots,
    const float* __restrict__ lng, const float* __restrict__ lnb,
    float* __restrict__ out){
  int lane = threadIdx.x & 63;
  int t = blockIdx.x * 4 + (threadIdx.x >> 6);
  const float* s0 = slots + (size_t)(2 * t) * DD;
  const float* s1 = s0 + DD;
  float y[16];
  float sum = 0.f, sq = 0.f;
  #pragma unroll
  for (int i = 0; i < 2; i++){
    int d = lane * 8 + i * 512;
    float4 p0 = *(const float4*)(s0 + d);
    float4 p1 = *(const float4*)(s0 + d + 4);
    float4 q0 = *(const float4*)(s1 + d);
    float4 q1 = *(const float4*)(s1 + d + 4);
    y[i*8+0]=p0.x+q0.x; y[i*8+1]=p0.y+q0.y; y[i*8+2]=p0.z+q0.z; y[i*8+3]=p0.w+q0.w;
    y[i*8+4]=p1.x+q1.x; y[i*8+5]=p1.y+q1.y; y[i*8+6]=p1.z+q1.z; y[i*8+7]=p1.w+q1.w;
  }
  #pragma unroll
  for (int j = 0; j < 16; j++){ sum += y[j]; sq += y[j]*y[j]; }
  #pragma unroll
  for (int off = 32; off > 0; off >>= 1){
    sum += __shfl_xor(sum, off, 64);
    sq  += __shfl_xor(sq,  off, 64);
  }
  float mu = sum * (1.0f / DD);
  float var = sq * (1.0f / DD) - mu * mu;
  float rs = 1.0f / sqrtf(var + 1e-5f);
  #pragma unroll
  for (int i = 0; i < 2; i++){
    int d = lane * 8 + i * 512;
    float4 g0 = *(const float4*)(lng + d), g1 = *(const float4*)(lng + d + 4);
    float4 c0 = *(const float4*)(lnb + d), c1 = *(const float4*)(lnb + d + 4);
    float4 o0, o1;
    o0.x=(y[i*8+0]-mu)*rs*g0.x+c0.x; o0.y=(y[i*8+1]-mu)*rs*g0.y+c0.y;
    o0.z=(y[i*8+2]-mu)*rs*g0.z+c0.z; o0.w=(y[i*8+3]-mu)*rs*g0.w+c0.w;
    o1.x=(y[i*8+4]-mu)*rs*g1.x+c1.x; o1.y=(y[i*8+5]-mu)*rs*g1.y+c1.y;
    o1.z=(y[i*8+6]-mu)*rs*g1.z+c1.z; o1.w=(y[i*8+7]-mu)*rs*g1.w+c1.w;
    *(float4*)(out + (size_t)t * DD + d)     = o0;
    *(float4*)(out + (size_t)t * DD + d + 4) = o1;
  }
}

// ---------------------------------------------------------------- launcher
extern "C" void kernel_launch(void* const* d_in, const int* in_sizes, int n_in,
                              void* d_out, int out_size, void* d_ws, size_t ws_size,
                              hipStream_t stream){
  const float* x   = (const float*)d_in[0];
  const float* gw  = (const float*)d_in[1];
  const float* gb  = (const float*)d_in[2];
  const float* w1  = (const float*)d_in[3];
  const float* b1  = (const float*)d_in[4];
  const float* w2  = (const float*)d_in[5];
  const float* b2  = (const float*)d_in[6];
  const float* lng = (const float*)d_in[7];
  const float* lnb = (const float*)d_in[8];
  float* out = (float*)d_out;

  char* ws = (char*)d_ws;
  size_t off = 0;
  auto alloc = [&](size_t bytes) -> void* {
    void* p = ws + off;
    off = (off + bytes + 255) & ~(size_t)255;
    return p;
  };
  int*   meta   = (int*)  alloc(256 * 4);
  int*   rowmap = (int*)  alloc(MAXROWS * 4);
  float* rowp   = (float*)alloc(MAXROWS * 4);
  int*   tidx   = (int*)  alloc(2 * T_TOK * 4);
  float* tp     = (float*)alloc(2 * T_TOK * 4);
  u16*   Xb     = (u16*)  alloc((size_t)T_TOK * DD * 2);
  float* slots  = (float*)alloc((size_t)T_TOK * 2 * DD * 4);
  u16*   H      = (u16*)  alloc((size_t)MAXROWS * FF * 2);
  u16*   Wt     = (u16*)  alloc((size_t)EE * DD * FF * 2);  // W1^T then W2^T
  (void)ws_size; (void)in_sizes; (void)n_in; (void)out_size;

  hipMemsetAsync(slots, 0, (size_t)T_TOK * 2 * DD * 4, stream);  // atomic accum target

  k_gate_cvt<<<T_TOK / 4, 256, 0, stream>>>(x, gw, gb, tidx, tp, Xb);
  k_fillscan<<<1, 256, 0, stream>>>(tidx, tp, meta, rowmap, rowp);

  // W1: [E][D][F] -> Wt = [E][F][D]
  k_cvtw  <<<dim3(FF / 64, DD / 64, EE), 256, 0, stream>>>(w1, Wt, DD, FF);
  k_gemm_h<<<dim3(MAXTILES, FF / 128), 256, 0, stream>>>(Xb, Wt, b1, meta, rowmap, H);
  // W2: [E][F][D] -> Wt = [E][D][F]
  k_cvtw  <<<dim3(DD / 64, FF / 64, EE), 256, 0, stream>>>(w2, Wt, FF, DD);
  k_gemm_y<<<dim3(MAXTILES, DD / 128, 2), 256, 0, stream>>>(H, Wt, b2, meta, rowmap, rowp, slots);

  k_ln    <<<T_TOK / 4, 256, 0, stream>>>(slots, lng, lnb, out);
}